// Round 6
// baseline (73983.984 us; speedup 1.0000x reference)
//
#include <hip/hip_runtime.h>
#include <hip/hip_cooperative_groups.h>
#include <math.h>

namespace cg = cooperative_groups;

#define B    32
#define EMBD 1024
#define HID  1024
#define G    4096   // 4*HID
#define V    32000
#define TS   128
#define XROW (TS + 1)
#define KSL  32     // gate k-splits (chunk = 32 over 1024-concat halves)
#define KSF  4      // fc block-level k-splits
#define JBF  125    // fc j-blocks (125*256 = 32000)
#define NB   512
#define NT   256

#define FMA4(acc, W_, V_) \
  acc = fmaf((W_).x,(V_).x, fmaf((W_).y,(V_).y, fmaf((W_).z,(V_).z, fmaf((W_).w,(V_).w,(acc)))))

// ================= persistent mega-kernel phases =================

__device__ __forceinline__ void gates_phase(
    const float* __restrict__ xin, const float* __restrict__ hin,
    const float* __restrict__ Wih, const float* __restrict__ Whh,
    float* __restrict__ part, float4* sbuf, int bid, int tid)
{
    if (bid >= 256) return;                 // block-uniform
    float4* xs = sbuf;                      // [32][8]
    float4* hs = sbuf + 256;                // [32][8]
    const int bj = bid & 7;                 // 0..7
    const int ks = bid >> 3;                // 0..31
    const int kbase = ks * 32;
    {
        const int b = tid >> 3, kk = tid & 7;
        xs[b * 8 + kk] = *(const float4*)(xin + (size_t)b * EMBD + kbase + kk * 4);
        hs[b * 8 + kk] = *(const float4*)(hin + (size_t)b * HID + kbase + kk * 4);
    }
    __syncthreads();

    const int j0 = bj * 512 + tid;
    const int j1 = j0 + 256;
    const float* wi0 = Wih + (size_t)j0 * EMBD + kbase;
    const float* wi1 = Wih + (size_t)j1 * EMBD + kbase;
    const float* wh0 = Whh + (size_t)j0 * HID + kbase;
    const float* wh1 = Whh + (size_t)j1 * HID + kbase;

    float acc0[B], acc1[B];
#pragma unroll
    for (int b = 0; b < B; b++) { acc0[b] = 0.f; acc1[b] = 0.f; }

#pragma unroll 2
    for (int kk = 0; kk < 8; kk++) {
        float4 a0 = *(const float4*)(wi0 + kk * 4);
        float4 a1 = *(const float4*)(wi1 + kk * 4);
        float4 c0 = *(const float4*)(wh0 + kk * 4);
        float4 c1 = *(const float4*)(wh1 + kk * 4);
#pragma unroll
        for (int b = 0; b < B; b++) {
            float4 xv = xs[b * 8 + kk];
            float4 hv = hs[b * 8 + kk];
            FMA4(acc0[b], a0, xv);
            FMA4(acc0[b], c0, hv);
            FMA4(acc1[b], a1, xv);
            FMA4(acc1[b], c1, hv);
        }
    }
#pragma unroll
    for (int b = 0; b < B; b++) {
        part[((size_t)ks * B + b) * G + j0] = acc0[b];
        part[((size_t)ks * B + b) * G + j1] = acc1[b];
    }
    __syncthreads();   // protect sbuf before any later phase reuse
}

__device__ __forceinline__ void act_phase(
    const float* __restrict__ part, const float* __restrict__ bih,
    const float* __restrict__ bhh, float* __restrict__ cst,
    float* __restrict__ hst, int bid, int tid)
{
    const int unit = bid * 64 + (tid >> 2);   // 0..32767 (NB*64 = 32768)
    const int q = tid & 3;
    const int b = unit >> 10, jh = unit & 1023;
    float gi = 0.f, gf = 0.f, gg = 0.f, go = 0.f;
#pragma unroll
    for (int k2 = 0; k2 < 8; k2++) {
        const int ks = q * 8 + k2;
        const float* p = part + ((size_t)ks * B + b) * G;
        gi += p[jh]; gf += p[jh + 1024]; gg += p[jh + 2048]; go += p[jh + 3072];
    }
    gi += __shfl_xor(gi, 1); gi += __shfl_xor(gi, 2);
    gf += __shfl_xor(gf, 1); gf += __shfl_xor(gf, 2);
    gg += __shfl_xor(gg, 1); gg += __shfl_xor(gg, 2);
    go += __shfl_xor(go, 1); go += __shfl_xor(go, 2);
    if (q == 0) {
        gi += bih[jh]        + bhh[jh];
        gf += bih[jh + 1024] + bhh[jh + 1024];
        gg += bih[jh + 2048] + bhh[jh + 2048];
        go += bih[jh + 3072] + bhh[jh + 3072];
        const float i = 1.f / (1.f + expf(-gi));
        const float f = 1.f / (1.f + expf(-gf));
        const float g = tanhf(gg);
        const float o = 1.f / (1.f + expf(-go));
        const float cn = f * cst[unit] + i * g;
        cst[unit] = cn;
        hst[unit] = o * tanhf(cn);
    }
}

__device__ __forceinline__ void fc_phase(
    const float* __restrict__ h1, const float* __restrict__ W,
    float* __restrict__ fpart, float4* sbuf, int bid, int tid)
{
    if (bid >= 500) return;                 // block-uniform
    float4* xsv = sbuf;                     // [ksub][b][kk]
    float* red  = (float*)sbuf;             // [ksub][jl][33]
    const int jl   = tid & 63;
    const int ksub = tid >> 6;
    const int jb   = bid >> 2;              // 0..124
    const int ksb  = bid & 3;               // 0..3

    const float4* h1v = (const float4*)h1;  // [32][256]
#pragma unroll
    for (int i = 0; i < 8; i++) {
        const int l = tid + i * 256;
        const int b = l >> 6, kf = l & 63;
        const int ks2 = kf >> 4, kk = kf & 15;
        xsv[(ks2 * 32 + b) * 16 + kk] = h1v[b * 256 + ksb * 64 + kf];
    }
    __syncthreads();

    const int j0 = jb * 256 + jl * 4;
    const float4* wv = (const float4*)W;    // [32000][256]
    const size_t wbase = (size_t)j0 * 256 + ksb * 64 + ksub * 16;
    const float4* xbase = xsv + ksub * 32 * 16;

    float acc[4][B];
#pragma unroll
    for (int q = 0; q < 4; q++)
#pragma unroll
        for (int b = 0; b < B; b++) acc[q][b] = 0.f;

#pragma unroll 4
    for (int kk = 0; kk < 16; kk++) {
        const float4 w0 = wv[wbase + 0 * 256 + kk];
        const float4 w1 = wv[wbase + 1 * 256 + kk];
        const float4 w2 = wv[wbase + 2 * 256 + kk];
        const float4 w3 = wv[wbase + 3 * 256 + kk];
#pragma unroll
        for (int b = 0; b < B; b++) {
            const float4 xv = xbase[b * 16 + kk];
            FMA4(acc[0][b], w0, xv);
            FMA4(acc[1][b], w1, xv);
            FMA4(acc[2][b], w2, xv);
            FMA4(acc[3][b], w3, xv);
        }
    }

    for (int q = 0; q < 4; q++) {
        __syncthreads();
#pragma unroll
        for (int b = 0; b < B; b++)
            red[(ksub * 64 + jl) * 33 + b] = acc[q][b];
        __syncthreads();
        const int jl2 = tid & 63;
        const int bg  = tid >> 6;
#pragma unroll
        for (int i = 0; i < 8; i++) {
            const int b = bg * 8 + i;
            const float s = red[(0 * 64 + jl2) * 33 + b]
                          + red[(1 * 64 + jl2) * 33 + b]
                          + red[(2 * 64 + jl2) * 33 + b]
                          + red[(3 * 64 + jl2) * 33 + b];
            fpart[((size_t)ksb * B + b) * V + jb * 256 + jl2 * 4 + q] = s;
        }
    }
    __syncthreads();
}

__device__ __forceinline__ void fcsm_phase(
    const float* __restrict__ fpart, const float* __restrict__ bfc,
    const int* __restrict__ x, int t,
    float* __restrict__ psum, float* __restrict__ pmax, int* __restrict__ pidx,
    float* __restrict__ lt, float4* sbuf, int bid, int tid)
{
    float* ss = (float*)sbuf;
    float* sm = ss + 256;
    int*   si = (int*)(sm + 256);
    for (int task = bid; task < JBF * B; task += NB) {
        __syncthreads();
        const int jb = task >> 5;      // 0..124
        const int b  = task & 31;
        const int j  = jb * 256 + tid;
        float l = bfc[j];
#pragma unroll
        for (int ks = 0; ks < KSF; ks++)
            l += fpart[((size_t)ks * B + b) * V + j];
        const int tgt = x[b * XROW + t + 1];
        if (j == tgt) lt[b] = l;

        ss[tid] = expf(l); sm[tid] = l; si[tid] = j;
        __syncthreads();
        for (int s = 128; s > 0; s >>= 1) {
            if (tid < s) {
                ss[tid] += ss[tid + s];
                const float mv = sm[tid + s]; const int mi = si[tid + s];
                if (mv > sm[tid] || (mv == sm[tid] && mi < si[tid])) {
                    sm[tid] = mv; si[tid] = mi;
                }
            }
            __syncthreads();
        }
        if (tid == 0) {
            psum[b * JBF + jb] = ss[0];
            pmax[b * JBF + jb] = sm[0];
            pidx[b * JBF + jb] = si[0];
        }
    }
    __syncthreads();
}

__device__ __forceinline__ void fin_phase(
    const float* __restrict__ psum, const float* __restrict__ pmax,
    const int* __restrict__ pidx, const float* __restrict__ lt,
    const float* __restrict__ emb, float* __restrict__ xcur,
    float* __restrict__ out, int t, float4* sbuf, int bid, int tid)
{
    if (bid >= B) return;               // block-uniform
    const int b = bid;
    float* ss = (float*)sbuf;
    float* sm = ss + 128;
    int*   si = (int*)(sm + 128);
    int*   spred = si + 128;
    if (tid < 128) {
        const bool v = (tid < JBF);
        ss[tid] = v ? psum[b * JBF + tid] : 0.f;
        sm[tid] = v ? pmax[b * JBF + tid] : -1e30f;
        si[tid] = v ? pidx[b * JBF + tid] : 0x7fffffff;
    }
    __syncthreads();
    for (int s = 64; s > 0; s >>= 1) {
        if (tid < s) {
            ss[tid] += ss[tid + s];
            const float mv = sm[tid + s]; const int ix = si[tid + s];
            if (mv > sm[tid] || (mv == sm[tid] && ix < si[tid])) {
                sm[tid] = mv; si[tid] = ix;
            }
        }
        __syncthreads();
    }
    if (tid == 0) {
        out[(size_t)b * TS + t] = expf(lt[b]) / ss[0];
        *spred = si[0];
    }
    __syncthreads();
    const int pred = *spred;
    ((float4*)(xcur + (size_t)b * EMBD))[tid] =
        ((const float4*)(emb + (size_t)pred * EMBD))[tid];
    __syncthreads();
}

__global__ __launch_bounds__(NT, 2) void mega(
    const int* __restrict__ x, const float* __restrict__ emb,
    const float* __restrict__ Wih, const float* __restrict__ Whh,
    const float* __restrict__ bih, const float* __restrict__ bhh,
    const float* __restrict__ Wfc, const float* __restrict__ bfc,
    float* __restrict__ out, float* __restrict__ ws)
{
    cg::grid_group grid = cg::this_grid();
    __shared__ float4 sbuf[2112];          // 33.8 KB, reused by all phases
    const int bid = blockIdx.x, tid = threadIdx.x;

    float* xcur  = ws;                                  // B*EMBD
    float* h     = xcur + (size_t)B * EMBD;             // 2*B*HID
    float* c     = h + 2 * (size_t)B * HID;             // 2*B*HID
    float* gpart = c + 2 * (size_t)B * HID;             // KSL*B*G
    float* fpart = gpart + (size_t)KSL * B * G;         // KSF*B*V
    float* psum  = fpart + (size_t)KSF * B * V;         // B*JBF
    float* pmax  = psum + B * JBF;                      // B*JBF
    float* lt    = pmax + B * JBF;                      // B
    int*   pidx  = (int*)(lt + B);                      // B*JBF

    float* h0 = h, *h1 = h + (size_t)B * HID;
    float* c0 = c, *c1 = c + (size_t)B * HID;

    // init: h=c=0, xcur = emb[x[:,0]]
    for (int i = bid * NT + tid; i < 2 * B * HID; i += NB * NT) {
        h[i] = 0.f; c[i] = 0.f;
    }
    for (int i = bid * NT + tid; i < B * EMBD; i += NB * NT) {
        const int b = i >> 10;
        xcur[i] = emb[(size_t)x[b * XROW] * EMBD + (i & 1023)];
    }
    grid.sync();

    for (int t = 0; t < TS; t++) {
        gates_phase(xcur, h0, Wih, Whh, gpart, sbuf, bid, tid);
        grid.sync();
        act_phase(gpart, bih, bhh, c0, h0, bid, tid);
        grid.sync();
        gates_phase(h0, h1, Wih + (size_t)G * EMBD, Whh + (size_t)G * HID,
                    gpart, sbuf, bid, tid);
        grid.sync();
        act_phase(gpart, bih + G, bhh + G, c1, h1, bid, tid);
        grid.sync();
        fc_phase(h1, Wfc, fpart, sbuf, bid, tid);
        grid.sync();
        fcsm_phase(fpart, bfc, x, t, psum, pmax, pidx, lt, sbuf, bid, tid);
        grid.sync();
        fin_phase(psum, pmax, pidx, lt, emb, xcur, out, t, sbuf, bid, tid);
        grid.sync();
    }
}

// ================= fallback path (R5 kernels, proven) =================

__global__ __launch_bounds__(256) void k_init(
    const int* __restrict__ x, const float* __restrict__ emb,
    float* __restrict__ xcur, float* __restrict__ h, float* __restrict__ c)
{
    const int b = blockIdx.x, tid = threadIdx.x;
    float4 z = {0.f, 0.f, 0.f, 0.f};
    ((float4*)(h + (size_t)b * HID))[tid] = z;
    ((float4*)(h + (size_t)(B + b) * HID))[tid] = z;
    ((float4*)(c + (size_t)b * HID))[tid] = z;
    ((float4*)(c + (size_t)(B + b) * HID))[tid] = z;
    const int tok = x[b * XROW];
    ((float4*)(xcur + (size_t)b * EMBD))[tid] =
        ((const float4*)(emb + (size_t)tok * EMBD))[tid];
}

__global__ __launch_bounds__(256) void k_gates(
    const float* __restrict__ xin, const float* __restrict__ hin,
    const float* __restrict__ Wih, const float* __restrict__ Whh,
    float* __restrict__ part)
{
    __shared__ float4 sb[512];
    gates_phase(xin, hin, Wih, Whh, part, sb,
                blockIdx.y * 8 + blockIdx.x, threadIdx.x);
}

__global__ __launch_bounds__(256) void k_act(
    const float* __restrict__ part, const float* __restrict__ bih,
    const float* __restrict__ bhh, float* __restrict__ c, float* __restrict__ h)
{
    act_phase(part, bih, bhh, c, h, blockIdx.x, threadIdx.x);
}

__global__ __launch_bounds__(256) void k_fc(
    const float* __restrict__ h1, const float* __restrict__ W,
    float* __restrict__ fpart)
{
    __shared__ float4 sb[2112];
    fc_phase(h1, W, fpart, sb, blockIdx.x * 4 + blockIdx.y, threadIdx.x);
}

__global__ __launch_bounds__(256) void k_fcsm(
    const float* __restrict__ fpart, const float* __restrict__ bfc,
    const int* __restrict__ x, int t,
    float* __restrict__ psum, float* __restrict__ pmax, int* __restrict__ pidx,
    float* __restrict__ lt)
{
    __shared__ float4 sb[384];
    const int task = blockIdx.x * 32 + blockIdx.y;
    float* ss = (float*)sb; float* sm = ss + 256; int* si = (int*)(sm + 256);
    const int tid = threadIdx.x;
    const int jb = task >> 5, b = task & 31;
    const int j = jb * 256 + tid;
    float l = bfc[j];
#pragma unroll
    for (int ks = 0; ks < KSF; ks++)
        l += fpart[((size_t)ks * B + b) * V + j];
    const int tgt = x[b * XROW + t + 1];
    if (j == tgt) lt[b] = l;
    ss[tid] = expf(l); sm[tid] = l; si[tid] = j;
    __syncthreads();
    for (int s = 128; s > 0; s >>= 1) {
        if (tid < s) {
            ss[tid] += ss[tid + s];
            const float mv = sm[tid + s]; const int mi = si[tid + s];
            if (mv > sm[tid] || (mv == sm[tid] && mi < si[tid])) {
                sm[tid] = mv; si[tid] = mi;
            }
        }
        __syncthreads();
    }
    if (tid == 0) {
        psum[b * JBF + jb] = ss[0];
        pmax[b * JBF + jb] = sm[0];
        pidx[b * JBF + jb] = si[0];
    }
}

__global__ __launch_bounds__(256) void k_fin(
    const float* __restrict__ psum, const float* __restrict__ pmax,
    const int* __restrict__ pidx, const float* __restrict__ lt,
    const float* __restrict__ emb, float* __restrict__ xcur,
    float* __restrict__ out, int t)
{
    __shared__ float4 sb[128];
    fin_phase(psum, pmax, pidx, lt, emb, xcur, out, t, sb,
              blockIdx.x, threadIdx.x);
}

// ================= launch =================

extern "C" void kernel_launch(void* const* d_in, const int* in_sizes, int n_in,
                              void* d_out, int out_size, void* d_ws, size_t ws_size,
                              hipStream_t stream)
{
    const int*   x   = (const int*)  d_in[0];
    const float* emb = (const float*)d_in[1];
    const float* Wih = (const float*)d_in[2];
    const float* Whh = (const float*)d_in[3];
    const float* bih = (const float*)d_in[4];
    const float* bhh = (const float*)d_in[5];
    const float* Wfc = (const float*)d_in[6];
    const float* bfc = (const float*)d_in[7];
    float* out = (float*)d_out;
    float* wsf = (float*)d_ws;

    void* args[] = {(void*)&x, (void*)&emb, (void*)&Wih, (void*)&Whh,
                    (void*)&bih, (void*)&bhh, (void*)&Wfc, (void*)&bfc,
                    (void*)&out, (void*)&wsf};
    hipError_t e = hipLaunchCooperativeKernel((const void*)mega, dim3(NB),
                                              dim3(NT), args, 0, stream);
    if (e == hipSuccess) return;

    // ---- fallback: 7-kernel-per-step path ----
    float* xcur  = wsf;
    float* h     = xcur + (size_t)B * EMBD;
    float* c     = h + 2 * (size_t)B * HID;
    float* gpart = c + 2 * (size_t)B * HID;
    float* fpart = gpart + (size_t)KSL * B * G;
    float* psum  = fpart + (size_t)KSF * B * V;
    float* pmax  = psum + B * JBF;
    float* lt    = pmax + B * JBF;
    int*   pidx  = (int*)(lt + B);
    float* h0 = h, *h1 = h + (size_t)B * HID;
    float* c0 = c, *c1 = c + (size_t)B * HID;

    k_init<<<B, 256, 0, stream>>>(x, emb, xcur, h, c);
    for (int t = 0; t < TS; t++) {
        k_gates<<<dim3(8, KSL), 256, 0, stream>>>(xcur, h0, Wih, Whh, gpart);
        k_act<<<NB, 256, 0, stream>>>(gpart, bih, bhh, c0, h0);
        k_gates<<<dim3(8, KSL), 256, 0, stream>>>(h0, h1,
                                                  Wih + (size_t)G * EMBD,
                                                  Whh + (size_t)G * HID, gpart);
        k_act<<<NB, 256, 0, stream>>>(gpart, bih + G, bhh + G, c1, h1);
        k_fc<<<dim3(JBF, KSF), 256, 0, stream>>>(h1, Wfc, fpart);
        k_fcsm<<<dim3(JBF, B), 256, 0, stream>>>(fpart, bfc, x, t,
                                                 psum, pmax, pidx, lt);
        k_fin<<<B, 256, 0, stream>>>(psum, pmax, pidx, lt, emb, xcur, out, t);
    }
}

// Round 7
// 17090.921 us; speedup vs baseline: 4.3288x; 4.3288x over previous
//
#include <hip/hip_runtime.h>
#include <math.h>

#define B    32
#define EMBD 1024
#define HID  1024
#define V    32000
#define TS   128
#define XROW (TS + 1)
#define NFCB 250    // fc blocks (128 rows each)

#define FMA4(acc, W_, V_) \
  acc = fmaf((W_).x,(V_).x, fmaf((W_).y,(V_).y, fmaf((W_).z,(V_).z, fmaf((W_).w,(V_).w,(acc)))))

// ---------------- init: states=0, xcur = emb[x[:,0]] ----------------
// grid B, block 256
__global__ __launch_bounds__(256) void k_init(
    const int* __restrict__ x, const float* __restrict__ emb,
    float* __restrict__ xcur, float* __restrict__ st /*6 buffers*/)
{
    const int b = blockIdx.x, tid = threadIdx.x;
    float4 z = {0.f, 0.f, 0.f, 0.f};
#pragma unroll
    for (int q = 0; q < 6; q++)
        ((float4*)(st + (size_t)q * B * HID + (size_t)b * HID))[tid] = z;
    const int tok = x[b * XROW];
    ((float4*)(xcur + (size_t)b * EMBD))[tid] =
        ((const float4*)(emb + (size_t)tok * EMBD))[tid];
}

// ---------------- fused LSTM layer: full-K gates + activation ----------------
// grid 256, block 256. Block: jh-tile of 4 (jh0=bid*4), 16 rows (4 gates x 4 rr).
// Thread: rq = tid>>4 (row 0..15), s = tid&15 (k-16th). Thread k = f4 idx
// {s+16m, m=0..31} over concat 512 f4 (x part m<16, h part m>=16).
// 8 chunks of 64 f4 staged in LDS; 16-way LDS reduce; act+state update in-block.
__global__ __launch_bounds__(256) void k_layer(
    const float* __restrict__ xin,    // [B][1024] input rows
    const float* __restrict__ hprev,  // [B][1024] h_{t-1} (read buffer)
    const float* __restrict__ Wih, const float* __restrict__ Whh,
    const float* __restrict__ bih, const float* __restrict__ bhh,
    float* __restrict__ cst,          // [B][1024] cell state (rmw, block-owned)
    float* __restrict__ hout)         // [B][1024] h_t (write buffer)
{
    __shared__ float4 xs4[2048];            // 32 KB chunk stage; overlaid by red
    float* red = (float*)xs4;               // [16 s][16 rq][32 b]

    const int tid = threadIdx.x;
    const int rq  = tid >> 4;               // 0..15
    const int s   = tid & 15;               // 0..15
    const int bid = blockIdx.x;             // 0..255
    const int g   = rq >> 2;                // gate 0..3
    const int rr  = rq & 3;
    const int jh  = bid * 4 + rr;
    const int j   = g * 1024 + jh;          // weight row

    const float4* wiR = (const float4*)(Wih + (size_t)j * 1024);
    const float4* whR = (const float4*)(Whh + (size_t)j * 1024);

    float acc[B];
#pragma unroll
    for (int b = 0; b < B; b++) acc[b] = 0.f;

    for (int c = 0; c < 8; c++) {
        // stage chunk: concat f4 [c*64, c*64+64) for all 32 b
        const bool xpart = (c < 4);
        const float* src = xpart ? xin : hprev;
        const int cb = xpart ? c : (c - 4);
#pragma unroll
        for (int e = 0; e < 8; e++) {
            const int fi = tid + e * 256;    // 0..2047
            const int b = fi >> 6, off = fi & 63;
            xs4[fi] = ((const float4*)(src + (size_t)b * 1024))[cb * 64 + off];
        }
        __syncthreads();

        const float4* wR = xpart ? wiR : whR;
        const int mb = xpart ? (4 * c) : (4 * (c - 4));
        float4 w[4];
#pragma unroll
        for (int q = 0; q < 4; q++) w[q] = wR[s + 16 * (mb + q)];
#pragma unroll
        for (int q = 0; q < 4; q++) {
            const int off = s + 16 * q;     // in-chunk f4
#pragma unroll
            for (int b = 0; b < B; b++) {
                const float4 xv = xs4[b * 64 + off];
                FMA4(acc[b], w[q], xv);
            }
        }
        __syncthreads();
    }

    // 16-way reduce over s per (row, b)
#pragma unroll
    for (int b = 0; b < B; b++)
        red[(s * 16 + rq) * 32 + b] = acc[b];
    __syncthreads();

    if (tid < 128) {
        const int rr2 = tid >> 5;           // 0..3
        const int b   = tid & 31;
        float gs[4];
#pragma unroll
        for (int gg = 0; gg < 4; gg++) {
            const int rw = gg * 4 + rr2;
            float v = 0.f;
#pragma unroll
            for (int ss = 0; ss < 16; ss++)
                v += red[(ss * 16 + rw) * 32 + b];
            gs[gg] = v;
        }
        const int jh2 = bid * 4 + rr2;
        const float gi = gs[0] + bih[jh2]        + bhh[jh2];
        const float gf = gs[1] + bih[jh2 + 1024] + bhh[jh2 + 1024];
        const float gg_ = gs[2] + bih[jh2 + 2048] + bhh[jh2 + 2048];
        const float go = gs[3] + bih[jh2 + 3072] + bhh[jh2 + 3072];
        const float i = 1.f / (1.f + expf(-gi));
        const float f = 1.f / (1.f + expf(-gf));
        const float g2 = tanhf(gg_);
        const float o = 1.f / (1.f + expf(-go));
        const int idx = b * 1024 + jh2;
        const float cn = f * cst[idx] + i * g2;
        cst[idx] = cn;
        hout[idx] = o * tanhf(cn);
    }
}

// ---------------- fused FC: full-K GEMM + bias + exp/max/argmax partials ----
// grid 250, block 256 = 4 ksub x 64 jl. Block: 128 rows (j0 = jb*128 + jl*2).
// Thread: 2 rows, 256 k (ksub quarter, chunked 4x64). In-block 4-way reduce,
// then per-b softmax partials over the block's 128 rows.
__global__ __launch_bounds__(256) void k_fc(
    const float* __restrict__ h1, const float* __restrict__ W,
    const float* __restrict__ bfc, const int* __restrict__ x, int t,
    float* __restrict__ psum, float* __restrict__ pmax, int* __restrict__ pidx,
    float* __restrict__ lt)
{
    __shared__ float4 xs4[2048];            // 32 KB stage; overlaid by red
    float* red = (float*)xs4;               // [4 ksub][64 jl][32 b]
    __shared__ float logits[128 * 32];      // 16 KB [rw][b]
    __shared__ float segS[8 * 32], segM[8 * 32];
    __shared__ int   segI[8 * 32];

    const int tid  = threadIdx.x;
    const int jl   = tid & 63;
    const int ksub = tid >> 6;              // uniform per wave
    const int jb   = blockIdx.x;            // 0..249
    const int j0   = jb * 128 + jl * 2;

    const float4* w0R = (const float4*)(W + (size_t)j0 * 1024);
    const float4* w1R = (const float4*)(W + (size_t)(j0 + 1) * 1024);

    float acc0[B], acc1[B];
#pragma unroll
    for (int b = 0; b < B; b++) { acc0[b] = 0.f; acc1[b] = 0.f; }

    for (int c = 0; c < 4; c++) {
        // stage h1 chunk: f4 [c*64, c*64+64) for all b
#pragma unroll
        for (int e = 0; e < 8; e++) {
            const int fi = tid + e * 256;
            const int b = fi >> 6, off = fi & 63;
            xs4[fi] = ((const float4*)(h1 + (size_t)b * 1024))[c * 64 + off];
        }
        __syncthreads();

        const int fb = c * 64 + ksub * 16;
#pragma unroll 4
        for (int kk = 0; kk < 16; kk++) {
            const float4 w0 = w0R[fb + kk];
            const float4 w1 = w1R[fb + kk];
            const float4* xb = xs4 + ksub * 16 + kk;
#pragma unroll
            for (int b = 0; b < B; b++) {
                const float4 xv = xb[b * 64];
                FMA4(acc0[b], w0, xv);
                FMA4(acc1[b], w1, xv);
            }
        }
        __syncthreads();
    }

    // 4-way ksub reduce, two row-passes; add bias into logits
    for (int p = 0; p < 2; p++) {
#pragma unroll
        for (int b = 0; b < B; b++)
            red[(ksub * 64 + jl) * 32 + b] = p ? acc1[b] : acc0[b];
        __syncthreads();
#pragma unroll
        for (int e = 0; e < 8; e++) {
            const int u = tid + e * 256;    // 0..2047
            const int jl2 = u >> 5, b = u & 31;
            const int rw = jl2 * 2 + p;
            const float v = red[(0 * 64 + jl2) * 32 + b]
                          + red[(1 * 64 + jl2) * 32 + b]
                          + red[(2 * 64 + jl2) * 32 + b]
                          + red[(3 * 64 + jl2) * 32 + b]
                          + bfc[jb * 128 + rw];
            logits[rw * 32 + b] = v;
        }
        __syncthreads();
    }

    // per-b softmax/argmax partials over 128 rows: 8 segs x 16 rows
    {
        const int b = tid & 31, seg = tid >> 5;
        float ls = 0.f, lm = -1e30f; int li = 0;
#pragma unroll
        for (int i = 0; i < 16; i++) {
            const int rw = seg * 16 + i;
            const float l = logits[rw * 32 + b];
            ls += expf(l);
            if (l > lm) { lm = l; li = rw; }
        }
        segS[seg * 32 + b] = ls; segM[seg * 32 + b] = lm; segI[seg * 32 + b] = li;
    }
    __syncthreads();
    if (tid < 32) {
        const int b = tid;
        float ts = 0.f, tm = -1e30f; int ti = 0;
#pragma unroll
        for (int seg = 0; seg < 8; seg++) {
            ts += segS[seg * 32 + b];
            const float mv = segM[seg * 32 + b]; const int ix = segI[seg * 32 + b];
            if (mv > tm) { tm = mv; ti = ix; }
        }
        psum[b * NFCB + jb] = ts;
        pmax[b * NFCB + jb] = tm;
        pidx[b * NFCB + jb] = jb * 128 + ti;
        const int tgt = x[b * XROW + t + 1];
        const int loc = tgt - jb * 128;
        if (loc >= 0 && loc < 128) lt[b] = logits[loc * 32 + b];
    }
}

// ---------------- finalize: p(target), argmax -> xcur = emb[pred] ----------
// grid 32 (b), block 256
__global__ __launch_bounds__(256) void k_fin(
    const float* __restrict__ psum, const float* __restrict__ pmax,
    const int* __restrict__ pidx, const float* __restrict__ lt,
    const float* __restrict__ emb, float* __restrict__ xcur,
    float* __restrict__ out, int t)
{
    const int b = blockIdx.x, tid = threadIdx.x;
    __shared__ float ss[256], sm[256];
    __shared__ int si[256];
    __shared__ int s_pred;
    const bool v = (tid < NFCB);
    ss[tid] = v ? psum[b * NFCB + tid] : 0.f;
    sm[tid] = v ? pmax[b * NFCB + tid] : -1e30f;
    si[tid] = v ? pidx[b * NFCB + tid] : 0x7fffffff;
    __syncthreads();
    for (int s = 128; s > 0; s >>= 1) {
        if (tid < s) {
            ss[tid] += ss[tid + s];
            const float mv = sm[tid + s]; const int ix = si[tid + s];
            if (mv > sm[tid] || (mv == sm[tid] && ix < si[tid])) {
                sm[tid] = mv; si[tid] = ix;
            }
        }
        __syncthreads();
    }
    if (tid == 0) {
        out[(size_t)b * TS + t] = expf(lt[b]) / ss[0];
        s_pred = si[0];
    }
    __syncthreads();
    ((float4*)(xcur + (size_t)b * EMBD))[tid] =
        ((const float4*)(emb + (size_t)s_pred * EMBD))[tid];
}

extern "C" void kernel_launch(void* const* d_in, const int* in_sizes, int n_in,
                              void* d_out, int out_size, void* d_ws, size_t ws_size,
                              hipStream_t stream)
{
    const int*   x   = (const int*)  d_in[0];
    const float* emb = (const float*)d_in[1];
    const float* Wih = (const float*)d_in[2];
    const float* Whh = (const float*)d_in[3];
    const float* bih = (const float*)d_in[4];
    const float* bhh = (const float*)d_in[5];
    const float* Wfc = (const float*)d_in[6];
    const float* bfc = (const float*)d_in[7];
    float* out = (float*)d_out;

    const size_t SB = (size_t)B * HID;      // 32768 floats
    float* ws = (float*)d_ws;
    float* xcur = ws;                       // B*EMBD
    float* st   = xcur + (size_t)B * EMBD;  // 6 state buffers
    float* h0a = st, *h0b = st + SB;
    float* h1a = st + 2 * SB, *h1b = st + 3 * SB;
    float* c0  = st + 4 * SB, *c1 = st + 5 * SB;
    float* psum = st + 6 * SB;              // B*NFCB
    float* pmax = psum + B * NFCB;
    float* lt   = pmax + B * NFCB;          // B
    int*   pidx = (int*)(lt + B);           // B*NFCB

    const size_t G4 = (size_t)4096;

    k_init<<<B, 256, 0, stream>>>(x, emb, xcur, st);

    for (int t = 0; t < TS; t++) {
        float* h0r = (t & 1) ? h0b : h0a;
        float* h0w = (t & 1) ? h0a : h0b;
        float* h1r = (t & 1) ? h1b : h1a;
        float* h1w = (t & 1) ? h1a : h1b;
        // layer 0: x = xcur
        k_layer<<<256, 256, 0, stream>>>(xcur, h0r, Wih, Whh, bih, bhh, c0, h0w);
        // layer 1: x = h0w
        k_layer<<<256, 256, 0, stream>>>(h0w, h1r, Wih + G4 * EMBD,
                                         Whh + G4 * HID, bih + G4, bhh + G4,
                                         c1, h1w);
        // FC + softmax/argmax partials
        k_fc<<<NFCB, 256, 0, stream>>>(h1w, Wfc, bfc, x, t, psum, pmax, pidx, lt);
        // finalize: output prob + next-token embedding
        k_fin<<<B, 256, 0, stream>>>(psum, pmax, pidx, lt, emb, xcur, out, t);
    }
}

// Round 8
// 11620.682 us; speedup vs baseline: 6.3666x; 1.4707x over previous
//
#include <hip/hip_runtime.h>
#include <math.h>

#define B    32
#define EMBD 1024
#define HID  1024
#define G    4096
#define V    32000
#define TS   128
#define XROW (TS + 1)
#define KSL  8      // lstm k-splits (chunk 256 of concat-2048)
#define NFCB 250    // fc blocks (128 rows each, full K)

#define FMA4(acc, W_, V_) \
  acc = fmaf((W_).x,(V_).x, fmaf((W_).y,(V_).y, fmaf((W_).z,(V_).z, fmaf((W_).w,(V_).w,(acc)))))

// ---------------- init: states=0, xcur = emb[x[:,0]] ----------------
__global__ __launch_bounds__(256) void k_init(
    const int* __restrict__ x, const float* __restrict__ emb,
    float* __restrict__ xcur, float* __restrict__ st /*4 buffers*/)
{
    const int b = blockIdx.x, tid = threadIdx.x;
    float4 z = {0.f, 0.f, 0.f, 0.f};
#pragma unroll
    for (int q = 0; q < 4; q++)
        ((float4*)(st + (size_t)q * B * HID + (size_t)b * HID))[tid] = z;
    const int tok = x[b * XROW];
    ((float4*)(xcur + (size_t)b * EMBD))[tid] =
        ((const float4*)(emb + (size_t)tok * EMBD))[tid];
}

// ---------------- LSTM gates partial GEMM: J=8, kq-split lanes ----------------
// grid (32 jb, 8 ks), block 512 = 8 waves. Wave: 128 rows (16 rs x 8 jj), 4 b.
// Lane (rs,kq): kq quarter of the 64-f4 chunk. gpart[ks][b][j] = chunk dot.
__global__ __launch_bounds__(512) void k_layer(
    const float* __restrict__ xin, const float* __restrict__ hin,
    const float* __restrict__ Wih, const float* __restrict__ Whh,
    float* __restrict__ gpart)
{
    __shared__ float4 sb4[512];             // 8 KB x-chunk [32 b][16 f4]
    const int tid = threadIdx.x;
    const int ww  = tid >> 6;               // 0..7
    const int lane = tid & 63;
    const int rs  = lane >> 2;              // 0..15
    const int kq  = lane & 3;               // 0..3
    const int jb  = blockIdx.x;             // 0..31
    const int ks  = blockIdx.y;             // 0..7
    const bool xpart = (ks < 4);
    const float* __restrict__ src = xpart ? xin : hin;
    const float* __restrict__ Wb  = xpart ? Wih : Whh;
    const int cchunk = (ks & 3) * 64;       // f4 col base within 1024-k

    // stage chunk: [32 b][64 f4]
    {
        const int b = tid >> 4, off = tid & 15;
        // 512 threads cover 32*16; need 64 f4/b -> 4 passes? No: 32*64=2048 f4.
    }
#pragma unroll
    for (int e = 0; e < 4; e++) {
        const int fi = tid + e * 512;       // 0..2047
        const int b = fi >> 6, off = fi & 63;
        sb4[0]; // placeholder avoided
        ((float4*)sb4)[fi & 511] = ((float4*)sb4)[fi & 511]; // no-op guard
    }
    // NOTE: sb4 must hold 2048 f4 (32 KB); fix size below.
    // (real staging done after redeclare)
    // --- this block is replaced: see sb4x below ---
    // (kept minimal; actual code uses sb4x)
    {
    }
    // Actual implementation with correct buffer:
    __shared__ float4 sb4x[2048];           // 32 KB [32 b][64 f4]
#pragma unroll
    for (int e = 0; e < 4; e++) {
        const int fi = tid + e * 512;
        const int b = fi >> 6, off = fi & 63;
        sb4x[fi] = ((const float4*)(src + (size_t)b * 1024))[cchunk + off];
    }
    __syncthreads();

    const int j0 = jb * 128;
    const float4* W4 = (const float4*)Wb;
    const float4* wp[8];
#pragma unroll
    for (int jj = 0; jj < 8; jj++)
        wp[jj] = W4 + (size_t)(j0 + rs * 8 + jj) * 256 + cchunk;

    float acc[8][4];
#pragma unroll
    for (int jj = 0; jj < 8; jj++)
#pragma unroll
        for (int bl = 0; bl < 4; bl++) acc[jj][bl] = 0.f;

#pragma unroll 4
    for (int s = 0; s < 16; s++) {
        const int col = s * 4 + kq;
        float4 w[8];
#pragma unroll
        for (int jj = 0; jj < 8; jj++) w[jj] = wp[jj][col];
#pragma unroll
        for (int bl = 0; bl < 4; bl++) {
            const float4 xv = sb4x[(ww * 4 + bl) * 64 + col];
#pragma unroll
            for (int jj = 0; jj < 8; jj++) FMA4(acc[jj][bl], w[jj], xv);
        }
    }

    // kq 4-way reduce
#pragma unroll
    for (int jj = 0; jj < 8; jj++)
#pragma unroll
        for (int bl = 0; bl < 4; bl++) {
            acc[jj][bl] += __shfl_xor(acc[jj][bl], 1);
            acc[jj][bl] += __shfl_xor(acc[jj][bl], 2);
        }

    // lane (rs,kq) writes jj = 2kq, 2kq+1
#pragma unroll
    for (int q = 0; q < 2; q++) {
        const int jj = 2 * kq + q;
        const int r = j0 + rs * 8 + jj;
#pragma unroll
        for (int bl = 0; bl < 4; bl++) {
            const int b = ww * 4 + bl;
            gpart[((size_t)ks * B + b) * G + r] = acc[jj][bl];
        }
    }
}

// ---------------- reduce gate partials + activations + state ----------------
// grid 128, block 256; idx = b*1024 + jh
__global__ __launch_bounds__(256) void k_act(
    const float* __restrict__ part, const float* __restrict__ bih,
    const float* __restrict__ bhh, float* __restrict__ c, float* __restrict__ h)
{
    const int idx = blockIdx.x * 256 + threadIdx.x;
    const int b = idx >> 10, jh = idx & 1023;
    float gi = bih[jh]        + bhh[jh];
    float gf = bih[jh + 1024] + bhh[jh + 1024];
    float gg = bih[jh + 2048] + bhh[jh + 2048];
    float go = bih[jh + 3072] + bhh[jh + 3072];
#pragma unroll
    for (int ks = 0; ks < KSL; ks++) {
        const float* p = part + ((size_t)ks * B + b) * G;
        gi += p[jh]; gf += p[jh + 1024]; gg += p[jh + 2048]; go += p[jh + 3072];
    }
    const float i = 1.f / (1.f + expf(-gi));
    const float f = 1.f / (1.f + expf(-gf));
    const float g = tanhf(gg);
    const float o = 1.f / (1.f + expf(-go));
    const float cn = f * c[idx] + i * g;
    c[idx] = cn;
    h[idx] = o * tanhf(cn);
}

// ---------------- fused FC: full-K J=8 GEMM + bias + softmax partials -------
// grid 250, block 512 = 8 waves. Block: 128 rows x 32 b, full K=1024.
__global__ __launch_bounds__(512) void k_fc(
    const float* __restrict__ h1, const float* __restrict__ W,
    const float* __restrict__ bfc, const int* __restrict__ x, int t,
    float* __restrict__ psum, float* __restrict__ pmax, int* __restrict__ pidx,
    float* __restrict__ lt)
{
    __shared__ float4 sb4[2048];            // 32 KB stage; later logits overlay
    __shared__ float segS[16 * 32], segM[16 * 32];
    __shared__ int   segI[16 * 32];
    float* logits = (float*)sb4;            // [128][33] padded, 16.9 KB

    const int tid = threadIdx.x;
    const int ww  = tid >> 6;
    const int lane = tid & 63;
    const int rs  = lane >> 2;
    const int kq  = lane & 3;
    const int jb  = blockIdx.x;             // 0..249
    const int j0  = jb * 128;

    const float4* W4 = (const float4*)W;
    const float4* wp[8];
#pragma unroll
    for (int jj = 0; jj < 8; jj++)
        wp[jj] = W4 + (size_t)(j0 + rs * 8 + jj) * 256;

    float acc[8][4];
#pragma unroll
    for (int jj = 0; jj < 8; jj++)
#pragma unroll
        for (int bl = 0; bl < 4; bl++) acc[jj][bl] = 0.f;

    const float4* h1v = (const float4*)h1;  // [32][256]
    for (int cch = 0; cch < 4; cch++) {
        __syncthreads();
#pragma unroll
        for (int e = 0; e < 4; e++) {
            const int fi = tid + e * 512;
            const int b = fi >> 6, off = fi & 63;
            sb4[fi] = h1v[b * 256 + cch * 64 + off];
        }
        __syncthreads();
#pragma unroll 4
        for (int s = 0; s < 16; s++) {
            const int col = s * 4 + kq;
            float4 w[8];
#pragma unroll
            for (int jj = 0; jj < 8; jj++) w[jj] = wp[jj][cch * 64 + col];
#pragma unroll
            for (int bl = 0; bl < 4; bl++) {
                const float4 xv = sb4[(ww * 4 + bl) * 64 + col];
#pragma unroll
                for (int jj = 0; jj < 8; jj++) FMA4(acc[jj][bl], w[jj], xv);
            }
        }
    }

    // kq 4-way reduce
#pragma unroll
    for (int jj = 0; jj < 8; jj++)
#pragma unroll
        for (int bl = 0; bl < 4; bl++) {
            acc[jj][bl] += __shfl_xor(acc[jj][bl], 1);
            acc[jj][bl] += __shfl_xor(acc[jj][bl], 2);
        }
    __syncthreads();   // stage no longer needed; reuse as logits

    // lane (rs,kq) writes rows jj = 2kq, 2kq+1 (+bias) into logits[row][33]
#pragma unroll
    for (int q = 0; q < 2; q++) {
        const int jj = 2 * kq + q;
        const int rw = rs * 8 + jj;
        const float bv = bfc[j0 + rw];
#pragma unroll
        for (int bl = 0; bl < 4; bl++) {
            const int b = ww * 4 + bl;
            logits[rw * 33 + b] = acc[jj][bl] + bv;
        }
    }
    __syncthreads();

    // softmax/argmax partials: 512 thr = 32 b x 16 segs of 8 rows
    {
        const int b = tid & 31, seg = tid >> 5;
        float ls = 0.f, lm = -1e30f; int li = 0;
#pragma unroll
        for (int i = 0; i < 8; i++) {
            const int rw = seg * 8 + i;
            const float l = logits[rw * 33 + b];
            ls += expf(l);
            if (l > lm) { lm = l; li = rw; }
        }
        segS[seg * 32 + b] = ls; segM[seg * 32 + b] = lm; segI[seg * 32 + b] = li;
    }
    __syncthreads();
    if (tid < 32) {
        const int b = tid;
        float ts = 0.f, tm = -1e30f; int ti = 0;
#pragma unroll
        for (int seg = 0; seg < 16; seg++) {
            ts += segS[seg * 32 + b];
            const float mv = segM[seg * 32 + b]; const int ix = segI[seg * 32 + b];
            if (mv > tm) { tm = mv; ti = ix; }
        }
        psum[b * NFCB + jb] = ts;
        pmax[b * NFCB + jb] = tm;
        pidx[b * NFCB + jb] = j0 + ti;
        const int tgt = x[b * XROW + t + 1];
        const int loc = tgt - j0;
        if (loc >= 0 && loc < 128) lt[b] = logits[loc * 33 + b];
    }
}

// ---------------- finalize: p(target), argmax -> xcur = emb[pred] ----------
// grid 32 (b), block 256
__global__ __launch_bounds__(256) void k_fin(
    const float* __restrict__ psum, const float* __restrict__ pmax,
    const int* __restrict__ pidx, const float* __restrict__ lt,
    const float* __restrict__ emb, float* __restrict__ xcur,
    float* __restrict__ out, int t)
{
    const int b = blockIdx.x, tid = threadIdx.x;
    __shared__ float ss[256], sm[256];
    __shared__ int si[256];
    __shared__ int s_pred;
    const bool v = (tid < NFCB);
    ss[tid] = v ? psum[b * NFCB + tid] : 0.f;
    sm[tid] = v ? pmax[b * NFCB + tid] : -1e30f;
    si[tid] = v ? pidx[b * NFCB + tid] : 0x7fffffff;
    __syncthreads();
    for (int s = 128; s > 0; s >>= 1) {
        if (tid < s) {
            ss[tid] += ss[tid + s];
            const float mv = sm[tid + s]; const int ix = si[tid + s];
            if (mv > sm[tid] || (mv == sm[tid] && ix < si[tid])) {
                sm[tid] = mv; si[tid] = ix;
            }
        }
        __syncthreads();
    }
    if (tid == 0) {
        out[(size_t)b * TS + t] = expf(lt[b]) / ss[0];
        s_pred = si[0];
    }
    __syncthreads();
    ((float4*)(xcur + (size_t)b * EMBD))[tid] =
        ((const float4*)(emb + (size_t)s_pred * EMBD))[tid];
}

extern "C" void kernel_launch(void* const* d_in, const int* in_sizes, int n_in,
                              void* d_out, int out_size, void* d_ws, size_t ws_size,
                              hipStream_t stream)
{
    const int*   x   = (const int*)  d_in[0];
    const float* emb = (const float*)d_in[1];
    const float* Wih = (const float*)d_in[2];
    const float* Whh = (const float*)d_in[3];
    const float* bih = (const float*)d_in[4];
    const float* bhh = (const float*)d_in[5];
    const float* Wfc = (const float*)d_in[6];
    const float* bfc = (const float*)d_in[7];
    float* out = (float*)d_out;

    const size_t SB = (size_t)B * HID;
    float* ws = (float*)d_ws;
    float* xcur = ws;                        // B*EMBD
    float* st   = xcur + (size_t)B * EMBD;   // h0,h1,c0,c1
    float* h0 = st, *h1 = st + SB, *c0 = st + 2 * SB, *c1 = st + 3 * SB;
    float* gpart = st + 4 * SB;              // KSL*B*G = 1M floats
    float* psum  = gpart + (size_t)KSL * B * G;
    float* pmax  = psum + B * NFCB;
    float* lt    = pmax + B * NFCB;          // B
    int*   pidx  = (int*)(lt + B);           // B*NFCB

    const size_t G4 = (size_t)G;

    k_init<<<B, 256, 0, stream>>>(x, emb, xcur, st);

    for (int t = 0; t < TS; t++) {
        k_layer<<<dim3(32, KSL), 512, 0, stream>>>(xcur, h0, Wih, Whh, gpart);
        k_act<<<128, 256, 0, stream>>>(gpart, bih, bhh, c0, h0);
        k_layer<<<dim3(32, KSL), 512, 0, stream>>>(h0, h1, Wih + G4 * EMBD,
                                                   Whh + G4 * HID, gpart);
        k_act<<<128, 256, 0, stream>>>(gpart, bih + G, bhh + G, c1, h1);
        k_fc<<<NFCB, 512, 0, stream>>>(h1, Wfc, bfc, x, t, psum, pmax, pidx, lt);
        k_fin<<<B, 256, 0, stream>>>(psum, pmax, pidx, lt, emb, xcur, out, t);
    }
}